// Round 8
// baseline (270.055 us; speedup 1.0000x reference)
//
#include <hip/hip_runtime.h>

#define CHW 262144   // C*H*W = 256*32*32
#define HWD 1024     // H*W

typedef _Float16 v8h __attribute__((ext_vector_type(8)));
typedef _Float16 v4h __attribute__((ext_vector_type(4)));
typedef float    v4f __attribute__((ext_vector_type(4)));
typedef float    v16f __attribute__((ext_vector_type(16)));

// ws layout (float offsets), total 4235272 floats = 16.9 MB
static const unsigned OFF_ASQ  = 0;        // ||z_n||^2 [8192]
static const unsigned OFF_BSQ  = 8192;     // ||e_k||^2 [8192]
static const unsigned OFF_CNT  = 16384;    // counts (int, zeroed by k_prep) [8192]
static const unsigned OFF_HEAD = 24576;    // list heads, n+1, 0=end (int, zeroed) [8192]
static const unsigned OFF_NXT  = 32768;    // list next (int; fully written) [8192]
static const unsigned OFF_SCAL = 40960;    // [0]=loss_sum [1]=sum(cs) (zeroed) [8]
static const unsigned OFF_AH   = 40968;    // Ah fp16 [8192*256] (1048576 floats, 16B-aligned)
static const unsigned OFF_AM   = 1089544;  // Am fp16 (UNSCALED residuals since r5)
static const unsigned OFF_BH   = 2138120;  // Bh fp16
static const unsigned OFF_BM   = 3186696;  // Bm fp16 (UNSCALED residuals since r5)
// pdk u32[8192][128] (4 MB) lives in d_out's out_ema region (dead until k_fin writes it)

#define GLL(g, l) __builtin_amdgcn_global_load_lds( \
    (const __attribute__((address_space(1))) void*)(g), \
    (__attribute__((address_space(3))) void*)(l), 16, 0, 0)

// ---- stage 1: ||z||^2 | emb->bsq+fp16 split | z transpose+split | zero cnt/head/scal ----
// r5: residual matrices Am/Bm are stored UNSCALED (m' = fl16(x - h)); k_main folds all
// three products into one accumulator (S = acc * 2^-13). Sub-normal residuals contribute
// <1e-7 to z.e (vs 7.6e-6 key bucket) — harmless even if MFMA flushes denormals.
__global__ __launch_bounds__(256) void k_prep(const float* __restrict__ z,
        const float* __restrict__ emb, float* __restrict__ asq, float* __restrict__ bsq,
        _Float16* __restrict__ Bh, _Float16* __restrict__ Bm,
        _Float16* __restrict__ Ah, _Float16* __restrict__ Am,
        float* __restrict__ zerobase) {
    int bx = blockIdx.x;
    int t = threadIdx.x;
    if (bx < 32) {
        // ||z_n||^2 — EXACT sequential 256-chain (bits feed the argmin; do not reorder)
        int n = bx * 256 + t;
        const float* p = z + (size_t)(n >> 10) * CHW + (n & 1023);
        float s = 0.f;
        #pragma unroll 8
        for (int c = 0; c < 256; ++c) { float v = p[(size_t)c << 10]; s = fmaf(v, v, s); }
        asq[n] = s;
    } else if (bx < 2080) {
        int w = (bx - 32) * 4 + (t >> 6);
        int lane = t & 63;
        float4 v = *(const float4*)(emb + (size_t)w * 256 + lane * 4);
        float s = v.x * v.x;
        s = fmaf(v.y, v.y, s); s = fmaf(v.z, v.z, s); s = fmaf(v.w, v.w, s);
        #pragma unroll
        for (int m = 1; m < 64; m <<= 1) s += __shfl_xor(s, m, 64);
        if (lane == 0) bsq[w] = s;
        float e0 = v.x * 8192.0f, e1 = v.y * 8192.0f, e2 = v.z * 8192.0f, e3 = v.w * 8192.0f;
        _Float16 h0 = (_Float16)e0, h1 = (_Float16)e1, h2 = (_Float16)e2, h3 = (_Float16)e3;
        v4h hv = {h0, h1, h2, h3};
        v4h mv = {(_Float16)(e0 - (float)h0),
                  (_Float16)(e1 - (float)h1),
                  (_Float16)(e2 - (float)h2),
                  (_Float16)(e3 - (float)h3)};
        *(v4h*)(Bh + (size_t)w * 256 + lane * 4) = hv;
        *(v4h*)(Bm + (size_t)w * 256 + lane * 4) = mv;
    } else if (bx < 2592) {
        __shared__ float s[64][65];
        int blk = bx - 2080;
        int hw0 = (blk & 15) * 64;
        int c0  = ((blk >> 4) & 3) * 64;
        int b   = blk >> 6;
        #pragma unroll
        for (int ii = 0; ii < 16; ++ii) {
            int e = t + ii * 256;
            int c = e >> 6, x = e & 63;
            s[c][x] = z[(size_t)b * CHW + (size_t)(c0 + c) * HWD + hw0 + x];
        }
        __syncthreads();
        int n = t & 63, cseg = (t >> 6) * 16;
        _Float16 hbuf[16], mbuf[16];
        #pragma unroll
        for (int j = 0; j < 16; ++j) {
            float v = s[cseg + j][n];
            _Float16 h = (_Float16)v;
            float r = v - (float)h;
            hbuf[j] = h;
            mbuf[j] = (_Float16)r;
        }
        size_t off = ((size_t)b * 1024 + hw0 + n) * 256 + c0 + cseg;
        *(v8h*)(Ah + off)     = *(v8h*)(hbuf);
        *(v8h*)(Ah + off + 8) = *(v8h*)(hbuf + 8);
        *(v8h*)(Am + off)     = *(v8h*)(mbuf);
        *(v8h*)(Am + off + 8) = *(v8h*)(mbuf + 8);
    } else {
        // zero cnt[8192] + head[8192] + scal
        int idx = (bx - 2592) * 1024 + t * 4;   // 16 blocks cover 16384 u32
        *(float4*)(zerobase + idx) = (float4){0.f, 0.f, 0.f, 0.f};
        if (bx == 2592 && t == 0)
            *(float4*)(zerobase + 24576) = (float4){0.f, 0.f, 0.f, 0.f};   // scal[0..3]
    }
}

// ---- main: 256x256 tile, 512 threads (8 waves of 64x128), 32x32x16 MFMA, j-phases ----
// r8: shrink per-step WORK (r0-r7 showed ordering is not the lever):
//  * mfma_f32_32x32x16_f16: 48 MFMA/wave/step (was 96), ceiling 2382 TF (was 2075).
//    A/B frag: row=lane&31, k=(lane>>5)*8+e (generalizes the proven 16x16 mapping);
//    C/D (HW-verified m74/m101): col=lane&31, row=(reg&3)+8*(reg>>2)+4*(lane>>5).
//  * 4 j-phases per step {2-GLL stage quarter | 4 ds_read fb/fbm[j] | 12 MFMA} kill the
//    P3 B-re-read: 24 b128/wave/step (was 32).
//  * ONE barrier per step (8 total): stages for s+1 write buf(s+1), read-safe by the
//    top-of-s barrier; vmcnt(0) at top is free (its loads are a full step old).
// Numerics: per-acc chain hh(k0),hh(k1),hm'(k0),hm'(k1),m'h(k0),m'h(k1) — rounding
// drift vs r5-r7's K32 chains ~1e-10 unscaled, far inside the established budget.
__global__ __launch_bounds__(512, 2) void k_main(
        const _Float16* __restrict__ Ah, const _Float16* __restrict__ Am,
        const _Float16* __restrict__ Bh, const _Float16* __restrict__ Bm,
        const float* __restrict__ asq, const float* __restrict__ bsq,
        unsigned* __restrict__ pdk) {
    __shared__ _Float16 lds[65536];  // 128 KB: 2 bufs x 64 KB (AH 16K|AM 16K|BH 16K|BM 16K)
    // XCD-pinned swizzle (round-robin bid->XCD): xcd owns kt in [xcd*4, xcd*4+4)
    const int bid = blockIdx.x;
    const int xcd = bid & 7, sblk = bid >> 3;  // sblk in [0,128)
    const int kt = xcd * 4 + (sblk & 3);       // [0,32)
    const int nt = sblk >> 2;                  // [0,32)
    const int n0 = nt * 256, k0 = kt * 256;
    const int t = threadIdx.x;
    const int lane = t & 63, w = t >> 6;       // w in [0,8)
    const int wrow = w >> 1, wcol = w & 1;     // 4x2 wave grid, each wave 64 rows x 128 cols
    const int l31 = lane & 31, hi = lane >> 5;

    v16f acc[2][4];
    #pragma unroll
    for (int i = 0; i < 2; ++i)
        #pragma unroll
        for (int j = 0; j < 4; ++j)
            #pragma unroll
            for (int r = 0; r < 16; ++r) acc[i][j][r] = 0.f;

    // staging: thread t covers row-chunks t and t+512 per matrix (rows 0-127 / 128-255);
    // chunk swizzle c4 = (t&3) ^ ((row>>1)&3) is row-periodic mod 4 (128%4==0 -> same c40).
    const int row0 = t >> 2;                   // [0,128)
    const int c40 = (t & 3) ^ ((row0 >> 1) & 3);
    const char* gA  = (const char*)Ah + (size_t)(n0 + row0) * 512 + c40 * 16;
    const char* gAm = (const char*)Am + (size_t)(n0 + row0) * 512 + c40 * 16;
    const char* gB  = (const char*)Bh + (size_t)(k0 + row0) * 512 + c40 * 16;
    const char* gBm = (const char*)Bm + (size_t)(k0 + row0) * 512 + c40 * 16;

    // per-buf layout (halves): AH [0,8192) | AM [8192,16384) | BH [16384,24576) | BM [24576,32768)
    // 32x32x16 fragment addresses: row = base + tile*32 + l31, chunk = (kh*2+hi) ^ ((row>>1)&3)
    int sa[2][2], sb[4][2];
    #pragma unroll
    for (int i = 0; i < 2; ++i) {
        int mr = wrow * 64 + i * 32 + l31;     // [0,256)
        #pragma unroll
        for (int kh = 0; kh < 2; ++kh)
            sa[i][kh] = mr * 32 + ((((kh * 2 + hi)) ^ ((mr >> 1) & 3)) * 8);
    }
    #pragma unroll
    for (int j = 0; j < 4; ++j) {
        int nr = wcol * 128 + j * 32 + l31;    // [0,256)
        #pragma unroll
        for (int kh = 0; kh < 2; ++kh)
            sb[j][kh] = nr * 32 + ((((kh * 2 + hi)) ^ ((nr >> 1) & 3)) * 8);
    }

    auto stageA = [&](int s) {
        const size_t co = (size_t)s * 64;
        _Float16* l = lds + (s & 1) * 32768 + t * 8;
        GLL(gA + co,          l);
        GLL(gA + co + 65536,  l + 4096);
    };
    auto stageAm = [&](int s) {
        const size_t co = (size_t)s * 64;
        _Float16* l = lds + (s & 1) * 32768 + t * 8;
        GLL(gAm + co,         l + 8192);
        GLL(gAm + co + 65536, l + 12288);
    };
    auto stageB = [&](int s) {
        const size_t co = (size_t)s * 64;
        _Float16* l = lds + (s & 1) * 32768 + t * 8;
        GLL(gB + co,          l + 16384);
        GLL(gB + co + 65536,  l + 20480);
    };
    auto stageBm = [&](int s) {
        const size_t co = (size_t)s * 64;
        _Float16* l = lds + (s & 1) * 32768 + t * 8;
        GLL(gBm + co,         l + 24576);
        GLL(gBm + co + 65536, l + 28672);
    };

#define MFMA32(A, B, C) __builtin_amdgcn_mfma_f32_32x32x16_f16(A, B, C, 0, 0, 0)
    // per-acc chain order FROZEN within r8: hh(k0),hh(k1),hm'(k0),hm'(k1),m'h(k0),m'h(k1)
#define MJ(J, FB0, FB1, FBM0, FBM1) do { \
        acc[0][J] = MFMA32(fa00, FB0,  acc[0][J]); \
        acc[0][J] = MFMA32(fa01, FB1,  acc[0][J]); \
        acc[0][J] = MFMA32(fa00, FBM0, acc[0][J]); \
        acc[0][J] = MFMA32(fa01, FBM1, acc[0][J]); \
        acc[0][J] = MFMA32(fm00, FB0,  acc[0][J]); \
        acc[0][J] = MFMA32(fm01, FB1,  acc[0][J]); \
        acc[1][J] = MFMA32(fa10, FB0,  acc[1][J]); \
        acc[1][J] = MFMA32(fa11, FB1,  acc[1][J]); \
        acc[1][J] = MFMA32(fa10, FBM0, acc[1][J]); \
        acc[1][J] = MFMA32(fa11, FBM1, acc[1][J]); \
        acc[1][J] = MFMA32(fm10, FB0,  acc[1][J]); \
        acc[1][J] = MFMA32(fm11, FB1,  acc[1][J]); \
    } while (0)

    stageA(0); stageAm(0); stageB(0); stageBm(0);
    for (int s = 0; s < 8; ++s) {
        // own stage(s) loads are a full step old -> vmcnt(0) ~free; barrier makes buf(s)
        // readable by all and buf(s+1)(=buf(s-1)) writable (its readers all arrived here).
        asm volatile("s_waitcnt vmcnt(0)" ::: "memory");
        __builtin_amdgcn_s_barrier();
        __builtin_amdgcn_sched_barrier(0);     // stages must not hoist above the barrier
        const _Float16* L = lds + (s & 1) * 32768;

        // phase j0: stage A quarter; A frags + j0 B frags; 12 MFMA
        if (s < 7) stageA(s + 1);
        v8h fa00 = *(const v8h*)(L + sa[0][0]);
        v8h fa01 = *(const v8h*)(L + sa[0][1]);
        v8h fa10 = *(const v8h*)(L + sa[1][0]);
        v8h fa11 = *(const v8h*)(L + sa[1][1]);
        v8h fm00 = *(const v8h*)(L + 8192 + sa[0][0]);
        v8h fm01 = *(const v8h*)(L + 8192 + sa[0][1]);
        v8h fm10 = *(const v8h*)(L + 8192 + sa[1][0]);
        v8h fm11 = *(const v8h*)(L + 8192 + sa[1][1]);
        {
            v8h b0 = *(const v8h*)(L + 16384 + sb[0][0]);
            v8h b1 = *(const v8h*)(L + 16384 + sb[0][1]);
            v8h m0 = *(const v8h*)(L + 24576 + sb[0][0]);
            v8h m1 = *(const v8h*)(L + 24576 + sb[0][1]);
            MJ(0, b0, b1, m0, m1);
        }
        // phase j1
        if (s < 7) stageAm(s + 1);
        {
            v8h b0 = *(const v8h*)(L + 16384 + sb[1][0]);
            v8h b1 = *(const v8h*)(L + 16384 + sb[1][1]);
            v8h m0 = *(const v8h*)(L + 24576 + sb[1][0]);
            v8h m1 = *(const v8h*)(L + 24576 + sb[1][1]);
            MJ(1, b0, b1, m0, m1);
        }
        // phase j2
        if (s < 7) stageB(s + 1);
        {
            v8h b0 = *(const v8h*)(L + 16384 + sb[2][0]);
            v8h b1 = *(const v8h*)(L + 16384 + sb[2][1]);
            v8h m0 = *(const v8h*)(L + 24576 + sb[2][0]);
            v8h m1 = *(const v8h*)(L + 24576 + sb[2][1]);
            MJ(2, b0, b1, m0, m1);
        }
        // phase j3
        if (s < 7) stageBm(s + 1);
        {
            v8h b0 = *(const v8h*)(L + 16384 + sb[3][0]);
            v8h b1 = *(const v8h*)(L + 16384 + sb[3][1]);
            v8h m0 = *(const v8h*)(L + 24576 + sb[3][0]);
            v8h m1 = *(const v8h*)(L + 24576 + sb[3][1]);
            MJ(3, b0, b1, m0, m1);
        }
    }
#undef MJ
#undef MFMA32

    // epilogue: S = acc * 2^-13; d = fl(fl(a+b) - 2*S); key = ((d-a)*2^16+32768)<<13 | k
    // C/D map: n_local = wrow*64 + i*32 + (r&3)+8*(r>>2)+4*hi; col = wcol*128 + j*32 + l31
    float bvv[4];
    #pragma unroll
    for (int j = 0; j < 4; ++j) bvv[j] = bsq[k0 + wcol * 128 + j * 32 + l31];
    __syncthreads();                            // LDS reuse for key assembly
    unsigned* lrow = (unsigned*)lds;            // [1024]: (n>>7)*512 + g64*128 + (n&127)
    #pragma unroll
    for (int i = 0; i < 2; ++i) {
        #pragma unroll
        for (int r = 0; r < 16; ++r) {
            int n_loc = wrow * 64 + i * 32 + (r & 3) + 8 * (r >> 2) + 4 * hi;  // [0,256)
            float av_ = asq[n0 + n_loc];
            #pragma unroll
            for (int g = 0; g < 2; ++g) {
                unsigned best = 0xFFFFFFFFu;
                #pragma unroll
                for (int jj = 0; jj < 2; ++jj) {
                    const int j = g * 2 + jj;
                    float S = acc[i][j][r] * 1.220703125e-4f;   // * 2^-13
                    float dd = (av_ + bvv[j]) - 2.0f * S;
                    float gv = dd - av_;                        // exact (Sterbenz)
                    int mi = (int)(gv * 65536.0f) + 32768;      // exact integer
                    int col = k0 + wcol * 128 + j * 32 + l31;
                    unsigned key = ((unsigned)mi << 13) | (unsigned)col;
                    best = key < best ? key : best;
                }
                #pragma unroll
                for (int xm = 1; xm < 32; xm <<= 1) {           // reduce over the 32-lane group
                    unsigned o = __shfl_xor(best, xm, 64);
                    best = o < best ? o : best;
                }
                if (l31 == 0)
                    lrow[(n_loc >> 7) * 512 + (wcol * 2 + g) * 128 + (n_loc & 127)] = best;
            }
        }
    }
    __syncthreads();
    // dense coalesced store: pdk[(nt2)*128 + kt*4 + g64][n&127]; 1024 entries, 2/thread
    #pragma unroll
    for (int u = 0; u < 2; ++u) {
        int e = t + u * 512;
        pdk[((size_t)(nt * 2 + (e >> 9)) * 128 + kt * 4 + ((e >> 7) & 3)) * 128 + (e & 127)]
            = lrow[e];
    }
}

// ---- fused: per-block key reduce -> idx | lists/histogram/cs-sum (y==0) | z_q + loss ----
__global__ __launch_bounds__(256) void k_zqr(const unsigned* __restrict__ pdk,
        const float* __restrict__ z, const float* __restrict__ emb, const float* __restrict__ cs,
        float* __restrict__ out_idx, int* __restrict__ cnt,
        int* __restrict__ head, int* __restrict__ nxt,
        float* __restrict__ out_zq, float* __restrict__ scal) {
    const int bx = blockIdx.x, by = blockIdx.y;
    const int n0 = bx * 64, c00 = by * 64;
    const int lane = threadIdx.x & 63, g = threadIdx.x >> 6;
    const int nt = bx >> 1, mb = (bx & 1) * 64;

    // phase 1: min over 128 j-rows for the block's 64 n; lane l ends with n0+l's key
    unsigned mn = 0xFFFFFFFFu;
    const unsigned* base = pdk + (((size_t)nt * 128 + g * 32) << 7) + mb + lane;
    #pragma unroll 8
    for (int jj = 0; jj < 32; ++jj) {
        unsigned key = base[jj << 7];          // coalesced 256B run per j
        mn = key < mn ? key : mn;
    }
    __shared__ unsigned part[4][64];
    part[g][lane] = mn;
    __syncthreads();
    unsigned k0v = part[0][lane], k1v = part[1][lane];
    unsigned k2v = part[2][lane], k3v = part[3][lane];
    unsigned f01 = k0v < k1v ? k0v : k1v;
    unsigned f23 = k2v < k3v ? k2v : k3v;
    unsigned fkey = f01 < f23 ? f01 : f23;
    int idxn = (int)(fkey & 8191u);
    int n = n0 + lane;

    if (by == 0) {
        if (g == 0) {
            out_idx[n] = (float)idxn;
            atomicAdd(cnt + idxn, 1);
            int old = atomicExch(head + idxn, n + 1);   // 0 = end-of-list
            nxt[n] = old;
        } else if (g == 1) {
            float cv = cs[n];
            #pragma unroll
            for (int m = 1; m < 64; m <<= 1) cv += __shfl_xor(cv, m, 64);
            if (lane == 0) atomicAdd(scal + 1, cv);
        }
    }

    // phase 2: z_q gather + straight-through write + loss
    int b = n >> 10, hw = n & 1023;
    const float* zr = z + (size_t)b * CHW + hw;
    const float* er = emb + (size_t)idxn * 256;
    float* oz = out_zq + (size_t)b * CHW + hw;
    float ls = 0.f;
    #pragma unroll
    for (int q = 0; q < 4; ++q) {
        int c = c00 + g * 16 + q * 4;
        float4 e4 = *(const float4*)(er + c);
        float ev[4] = {e4.x, e4.y, e4.z, e4.w};
        #pragma unroll
        for (int r = 0; r < 4; ++r) {
            float zp = zr[(size_t)(c + r) << 10];
            float dif = ev[r] - zp;
            oz[(size_t)(c + r) << 10] = zp + dif;
            ls = fmaf(dif, dif, ls);
        }
    }
    #pragma unroll
    for (int m = 1; m < 64; m <<= 1) ls += __shfl_xor(ls, m, 64);
    __shared__ float red[4];
    if (lane == 0) red[g] = ls;
    __syncthreads();
    if (threadIdx.x == 0) atomicAdd(scal, red[0] + red[1] + red[2] + red[3]);
}

// ---- finalize: list-walk dw (zf reconstructed from Ah/Am), new_cs, ema, embedding, loss ----
__global__ __launch_bounds__(256) void k_fin(const float* __restrict__ cs, const float* __restrict__ ema,
        const int* __restrict__ head, const int* __restrict__ nxt,
        const _Float16* __restrict__ Ah, const _Float16* __restrict__ Am,
        const float* __restrict__ scal, const int* __restrict__ cnt,
        float* __restrict__ out_ncs, float* __restrict__ out_ema,
        float* __restrict__ out_emb, float* __restrict__ out_loss) {
    int k = blockIdx.x * 4 + (threadIdx.x >> 6);
    int lane = threadIdx.x & 63;
    // dw[k][:] = sum over assigned n of zf[n][:], zf ~= h + m' (m' unscaled residual)
    float4 dwv = {0.f, 0.f, 0.f, 0.f};
    int cur = head[k];
    while (cur) {
        int n = cur - 1;
        v4h hh = *(const v4h*)(Ah + (size_t)n * 256 + lane * 4);
        v4h mm = *(const v4h*)(Am + (size_t)n * 256 + lane * 4);
        dwv.x += (float)hh[0] + (float)mm[0];
        dwv.y += (float)hh[1] + (float)mm[1];
        dwv.z += (float)hh[2] + (float)mm[2];
        dwv.w += (float)hh[3] + (float)mm[3];
        cur = nxt[n];
    }
    const float C1 = (float)(1.0 - 0.99);
    const float KEPS = (float)(8192 * 1e-5);
    float ncs0v = cs[k] * 0.99f + C1 * (float)cnt[k];
    float nsum = 0.99f * scal[1] + C1 * 8192.0f;   // sum(counts) == N == 8192
    float ncs = (ncs0v + 1e-5f) / (nsum + KEPS) * nsum;
    if (lane == 0) out_ncs[k] = ncs;
    size_t base = (size_t)k * 256 + lane * 4;
    float4 e4 = *(const float4*)(ema + base);
    float r0 = e4.x * 0.99f + C1 * dwv.x;
    float r1 = e4.y * 0.99f + C1 * dwv.y;
    float r2 = e4.z * 0.99f + C1 * dwv.z;
    float r3 = e4.w * 0.99f + C1 * dwv.w;
    out_ema[base + 0] = r0; out_ema[base + 1] = r1; out_ema[base + 2] = r2; out_ema[base + 3] = r3;
    out_emb[base + 0] = r0 / ncs; out_emb[base + 1] = r1 / ncs;
    out_emb[base + 2] = r2 / ncs; out_emb[base + 3] = r3 / ncs;
    if (blockIdx.x == 0 && threadIdx.x == 0) {
        float m = scal[0] * (1.0f / 2097152.0f);
        out_loss[0] = m + 0.25f * m;
    }
}

extern "C" void kernel_launch(void* const* d_in, const int* in_sizes, int n_in,
                              void* d_out, int out_size, void* d_ws, size_t ws_size,
                              hipStream_t stream) {
    const float* z   = (const float*)d_in[0];
    const float* emb = (const float*)d_in[1];
    const float* cs  = (const float*)d_in[2];
    const float* ema = (const float*)d_in[3];
    float* out = (float*)d_out;
    float* wsf = (float*)d_ws;

    float* asq  = wsf + OFF_ASQ;
    float* bsq  = wsf + OFF_BSQ;
    int*   cnt  = (int*)(wsf + OFF_CNT);
    int*   head = (int*)(wsf + OFF_HEAD);
    int*   nxt  = (int*)(wsf + OFF_NXT);
    float* scal = wsf + OFF_SCAL;
    _Float16* Ah = (_Float16*)(wsf + OFF_AH);
    _Float16* Am = (_Float16*)(wsf + OFF_AM);
    _Float16* Bh = (_Float16*)(wsf + OFF_BH);
    _Float16* Bm = (_Float16*)(wsf + OFF_BM);

    float* out_zq   = out;                 // [2097152]
    float* out_loss = out + 2097152;       // [1]
    float* out_idx  = out + 2097153;       // [8192]
    float* out_ncs  = out + 2105345;       // [8192]
    float* out_ema  = out + 2113537;       // [2097152]
    float* out_emb  = out + 4210689;       // [2097152]

    // pdk (4 MB) aliases the dead out_ema region: written by k_main, read by k_zqr,
    // overwritten only later by k_fin's out_ema stores.
    unsigned* pdk = (unsigned*)(out + 2113540);   // 16B-aligned

    k_prep<<<2608, 256, 0, stream>>>(z, emb, asq, bsq, Bh, Bm, Ah, Am, wsf + OFF_CNT);
    k_main<<<1024, 512, 0, stream>>>(Ah, Am, Bh, Bm, asq, bsq, pdk);
    k_zqr<<<dim3(128, 4), 256, 0, stream>>>(pdk, z, emb, cs, out_idx, cnt, head, nxt, out_zq, scal);
    k_fin<<<2048, 256, 0, stream>>>(cs, ema, head, nxt, Ah, Am, scal, cnt, out_ncs, out_ema, out_emb, out_loss);
}

// Round 9
// 222.442 us; speedup vs baseline: 1.2140x; 1.2140x over previous
//
#include <hip/hip_runtime.h>

#define CHW 262144   // C*H*W = 256*32*32
#define HWD 1024     // H*W

typedef _Float16 v8h __attribute__((ext_vector_type(8)));
typedef _Float16 v4h __attribute__((ext_vector_type(4)));
typedef float    v4f __attribute__((ext_vector_type(4)));

// ws layout (float offsets), total 4235272 floats = 16.9 MB
static const unsigned OFF_ASQ  = 0;        // ||z_n||^2 [8192]
static const unsigned OFF_BSQ  = 8192;     // ||e_k||^2 [8192]
static const unsigned OFF_CNT  = 16384;    // counts (int, zeroed by k_prep) [8192]
static const unsigned OFF_HEAD = 24576;    // list heads, n+1, 0=end (int, zeroed) [8192]
static const unsigned OFF_NXT  = 32768;    // list next (int; fully written) [8192]
static const unsigned OFF_SCAL = 40960;    // [0]=loss_sum [1]=sum(cs) (zeroed) [8]
static const unsigned OFF_AH   = 40968;    // Ah fp16 [8192*256] (1048576 floats, 16B-aligned)
static const unsigned OFF_AM   = 1089544;  // Am fp16 (UNSCALED residuals since r5)
static const unsigned OFF_BH   = 2138120;  // Bh fp16
static const unsigned OFF_BM   = 3186696;  // Bm fp16 (UNSCALED residuals since r5)
// pdk u32[8192][128] (4 MB) lives in d_out's out_ema region (dead until k_fin writes it)

#define GLL(g, l) __builtin_amdgcn_global_load_lds( \
    (const __attribute__((address_space(1))) void*)(g), \
    (__attribute__((address_space(3))) void*)(l), 16, 0, 0)

// ---- stage 1: ||z||^2 | emb->bsq+fp16 split | z transpose+split | zero cnt/head/scal ----
// r5: residual matrices Am/Bm are stored UNSCALED (m' = fl16(x - h)); k_main folds all
// three products into one accumulator (S = acc * 2^-13).
// r9: transpose-section stores re-mapped so each 4-lane group writes a contiguous 128B
// row segment (was 16B at 512B stride). Same elements, same addresses, same values.
__global__ __launch_bounds__(256) void k_prep(const float* __restrict__ z,
        const float* __restrict__ emb, float* __restrict__ asq, float* __restrict__ bsq,
        _Float16* __restrict__ Bh, _Float16* __restrict__ Bm,
        _Float16* __restrict__ Ah, _Float16* __restrict__ Am,
        float* __restrict__ zerobase) {
    int bx = blockIdx.x;
    int t = threadIdx.x;
    if (bx < 32) {
        // ||z_n||^2 — EXACT sequential 256-chain (bits feed the argmin; do not reorder)
        int n = bx * 256 + t;
        const float* p = z + (size_t)(n >> 10) * CHW + (n & 1023);
        float s = 0.f;
        #pragma unroll 8
        for (int c = 0; c < 256; ++c) { float v = p[(size_t)c << 10]; s = fmaf(v, v, s); }
        asq[n] = s;
    } else if (bx < 2080) {
        int w = (bx - 32) * 4 + (t >> 6);
        int lane = t & 63;
        float4 v = *(const float4*)(emb + (size_t)w * 256 + lane * 4);
        float s = v.x * v.x;
        s = fmaf(v.y, v.y, s); s = fmaf(v.z, v.z, s); s = fmaf(v.w, v.w, s);
        #pragma unroll
        for (int m = 1; m < 64; m <<= 1) s += __shfl_xor(s, m, 64);
        if (lane == 0) bsq[w] = s;
        float e0 = v.x * 8192.0f, e1 = v.y * 8192.0f, e2 = v.z * 8192.0f, e3 = v.w * 8192.0f;
        _Float16 h0 = (_Float16)e0, h1 = (_Float16)e1, h2 = (_Float16)e2, h3 = (_Float16)e3;
        v4h hv = {h0, h1, h2, h3};
        v4h mv = {(_Float16)(e0 - (float)h0),
                  (_Float16)(e1 - (float)h1),
                  (_Float16)(e2 - (float)h2),
                  (_Float16)(e3 - (float)h3)};
        *(v4h*)(Bh + (size_t)w * 256 + lane * 4) = hv;
        *(v4h*)(Bm + (size_t)w * 256 + lane * 4) = mv;
    } else if (bx < 2592) {
        __shared__ float s[64][65];
        int blk = bx - 2080;
        int hw0 = (blk & 15) * 64;
        int c0  = ((blk >> 4) & 3) * 64;
        int b   = blk >> 6;
        #pragma unroll
        for (int ii = 0; ii < 16; ++ii) {
            int e = t + ii * 256;
            int c = e >> 6, x = e & 63;
            s[c][x] = z[(size_t)b * CHW + (size_t)(c0 + c) * HWD + hw0 + x];
        }
        __syncthreads();
        // r9 mapping: row n2 = t>>2, c-quad cq = (t&3)*16 -> lanes 0..3 write one
        // contiguous 128B row segment (fully-used 64B sectors). LDS re-read 2-way (free).
        int n2 = t >> 2, cq = (t & 3) * 16;
        _Float16 hbuf[16], mbuf[16];
        #pragma unroll
        for (int j = 0; j < 16; ++j) {
            float v = s[cq + j][n2];
            _Float16 h = (_Float16)v;
            float r = v - (float)h;
            hbuf[j] = h;
            mbuf[j] = (_Float16)r;
        }
        size_t off = ((size_t)b * 1024 + hw0 + n2) * 256 + c0 + cq;
        *(v8h*)(Ah + off)     = *(v8h*)(hbuf);
        *(v8h*)(Ah + off + 8) = *(v8h*)(hbuf + 8);
        *(v8h*)(Am + off)     = *(v8h*)(mbuf);
        *(v8h*)(Am + off + 8) = *(v8h*)(mbuf + 8);
    } else {
        // zero cnt[8192] + head[8192] + scal
        int idx = (bx - 2592) * 1024 + t * 4;   // 16 blocks cover 16384 u32
        *(float4*)(zerobase + idx) = (float4){0.f, 0.f, 0.f, 0.f};
        if (bx == 2592 && t == 0)
            *(float4*)(zerobase + 24576) = (float4){0.f, 0.f, 0.f, 0.f};   // scal[0..3]
    }
}

// ---- main: 256x256 tile, 512 threads (8 waves of 64x128), m201-cadence 3-phase ----
// r9: r7's product phases (P1 hh, P2 hm', P3 m'h — MFMA sequence IDENTICAL to r7 ->
// keys bit-identical) recast in the m201 cadence: per phase {ds_reads + stage quarter
// BETWEEN barriers; mid s_barrier; lgkmcnt(0)+sched_barrier; setprio(1) MFMA x32
// setprio(0); trail s_barrier}. Rendezvous moved one phase EARLY: P3-trail vmcnt(4)
// retires A,B of s+1 (M stays in flight); P1-trail vmcnt(2) retires M(s). Never drains
// to 0 mid-loop; ds_reads always overlap lagging waves' barrier arrival.
// FIFO ledger (per thread, issue order A(2),B(2),M(4) per step):
//  P1 top: A(s),B(s) retired (prev P3-trail). P1-trail: out=M(s)4+A(s+1)2 -> vmcnt(2).
//  P3-trail: out=M(s+1)? no: A(s+1)2+B(s+1)2+M(s+1)4=8 -> vmcnt(4) keeps M(s+1).
__global__ __launch_bounds__(512, 2) void k_main(
        const _Float16* __restrict__ Ah, const _Float16* __restrict__ Am,
        const _Float16* __restrict__ Bh, const _Float16* __restrict__ Bm,
        const float* __restrict__ asq, const float* __restrict__ bsq,
        unsigned* __restrict__ pdk) {
    __shared__ _Float16 lds[65536];  // 128 KB: 2 bufs x 64 KB (AH 16K|AM 16K|BH 16K|BM 16K)
    // XCD-pinned swizzle (round-robin bid->XCD): xcd owns kt in [xcd*4, xcd*4+4)
    const int bid = blockIdx.x;
    const int xcd = bid & 7, sblk = bid >> 3;  // sblk in [0,128)
    const int kt = xcd * 4 + (sblk & 3);       // [0,32)
    const int nt = sblk >> 2;                  // [0,32)
    const int n0 = nt * 256, k0 = kt * 256;
    const int t = threadIdx.x;
    const int lane = t & 63, w = t >> 6;       // w in [0,8)
    const int wrow = w >> 1, wcol = w & 1;     // 4x2 wave grid, each wave 64 rows x 128 cols
    const int lm = lane & 15, quad = lane >> 4;

    v4f acc[4][8];
    #pragma unroll
    for (int i = 0; i < 4; ++i)
        #pragma unroll
        for (int j = 0; j < 8; ++j) acc[i][j] = (v4f){0.f,0.f,0.f,0.f};

    // staging: thread t covers row-chunks t and t+512 per matrix (rows 0-127 / 128-255);
    // chunk swizzle c4 = (t&3) ^ ((row>>1)&3) is row-periodic mod 4 (128%4==0 -> same c40).
    const int row0 = t >> 2;                   // [0,128)
    const int c40 = (t & 3) ^ ((row0 >> 1) & 3);
    const char* gA  = (const char*)Ah + (size_t)(n0 + row0) * 512 + c40 * 16;
    const char* gAm = (const char*)Am + (size_t)(n0 + row0) * 512 + c40 * 16;
    const char* gB  = (const char*)Bh + (size_t)(k0 + row0) * 512 + c40 * 16;
    const char* gBm = (const char*)Bm + (size_t)(k0 + row0) * 512 + c40 * 16;

    // per-buf layout (halves): AH [0,8192) | AM [8192,16384) | BH [16384,24576) | BM [24576,32768)
    int sa[4], sb[8];
    #pragma unroll
    for (int i = 0; i < 4; ++i) {
        int mr = wrow * 64 + i * 16 + lm;      // [0,256)
        sa[i] = mr * 32 + ((quad ^ ((mr >> 1) & 3)) * 8);
    }
    #pragma unroll
    for (int j = 0; j < 8; ++j) {
        int nr = wcol * 128 + j * 16 + lm;     // [0,256)
        sb[j] = nr * 32 + ((quad ^ ((nr >> 1) & 3)) * 8);
    }

    // stage quarters for step s into buf (s&1): A = Ah (2 GLL), B = Bh (2), M = Am+Bm (4)
    auto stageA = [&](int s) {
        const size_t co = (size_t)s * 64;
        _Float16* l = lds + (s & 1) * 32768 + t * 8;
        GLL(gA + co,          l);
        GLL(gA + co + 65536,  l + 4096);
    };
    auto stageB = [&](int s) {
        const size_t co = (size_t)s * 64;
        _Float16* l = lds + (s & 1) * 32768 + t * 8;
        GLL(gB + co,          l + 16384);
        GLL(gB + co + 65536,  l + 20480);
    };
    auto stageM = [&](int s) {
        const size_t co = (size_t)s * 64;
        _Float16* l = lds + (s & 1) * 32768 + t * 8;
        GLL(gAm + co,         l + 8192);
        GLL(gAm + co + 65536, l + 12288);
        GLL(gBm + co,         l + 24576);
        GLL(gBm + co + 65536, l + 28672);
    };

#define MFMA16(A, B, C) __builtin_amdgcn_mfma_f32_16x16x32_f16(A, B, C, 0, 0, 0)

    // prologue: 8 GLLs in flight {A0(2), B0(2), M0(4)}; rendezvous A0,B0 (keep M0)
    stageA(0); stageB(0); stageM(0);
    asm volatile("s_waitcnt vmcnt(4)" ::: "memory");
    __builtin_amdgcn_s_barrier();

    #pragma unroll
    for (int s = 0; s < 8; ++s) {
        const _Float16* L = lds + (s & 1) * 32768;

        // ---- P1: hh. A(s),B(s) rendezvous'd at previous trail-bar ----
        v8h fa[4], fb[8];
        #pragma unroll
        for (int i = 0; i < 4; ++i) fa[i] = *(const v8h*)(L + sa[i]);
        #pragma unroll
        for (int j = 0; j < 8; ++j) fb[j] = *(const v8h*)(L + 16384 + sb[j]);
        if (s < 7) stageA(s + 1);
        __builtin_amdgcn_sched_barrier(0);
        __builtin_amdgcn_s_barrier();              // mid: reads overlap others' arrival
        asm volatile("s_waitcnt lgkmcnt(0)" ::: "memory");
        __builtin_amdgcn_sched_barrier(0);
        __builtin_amdgcn_s_setprio(1);
        #pragma unroll
        for (int j = 0; j < 8; ++j)
            #pragma unroll
            for (int i = 0; i < 4; ++i)
                acc[i][j] = MFMA16(fa[i], fb[j], acc[i][j]);
        __builtin_amdgcn_s_setprio(0);
        __builtin_amdgcn_sched_barrier(0);
        if (s < 7) { asm volatile("s_waitcnt vmcnt(2)" ::: "memory"); }
        else       { asm volatile("s_waitcnt vmcnt(0)" ::: "memory"); }
        __builtin_amdgcn_s_barrier();              // trail: M(s) rendezvous'd

        // ---- P2: hm'. fa live in regs; Bm(s) now readable ----
        v8h fbm[8];
        #pragma unroll
        for (int j = 0; j < 8; ++j) fbm[j] = *(const v8h*)(L + 24576 + sb[j]);
        if (s < 7) stageB(s + 1);
        __builtin_amdgcn_sched_barrier(0);
        __builtin_amdgcn_s_barrier();              // mid
        asm volatile("s_waitcnt lgkmcnt(0)" ::: "memory");
        __builtin_amdgcn_sched_barrier(0);
        __builtin_amdgcn_s_setprio(1);
        #pragma unroll
        for (int j = 0; j < 8; ++j)
            #pragma unroll
            for (int i = 0; i < 4; ++i)
                acc[i][j] = MFMA16(fa[i], fbm[j], acc[i][j]);
        __builtin_amdgcn_s_setprio(0);
        __builtin_amdgcn_sched_barrier(0);
        __builtin_amdgcn_s_barrier();              // trail (plain)

        // ---- P3: m'h. Am(s) retired at P1-trail; Bh(s) re-read ----
        v8h fam[4], fb2[8];
        #pragma unroll
        for (int i = 0; i < 4; ++i) fam[i] = *(const v8h*)(L + 8192 + sa[i]);
        #pragma unroll
        for (int j = 0; j < 8; ++j) fb2[j] = *(const v8h*)(L + 16384 + sb[j]);
        if (s < 7) stageM(s + 1);
        __builtin_amdgcn_sched_barrier(0);
        __builtin_amdgcn_s_barrier();              // mid
        asm volatile("s_waitcnt lgkmcnt(0)" ::: "memory");
        __builtin_amdgcn_sched_barrier(0);
        __builtin_amdgcn_s_setprio(1);
        #pragma unroll
        for (int j = 0; j < 8; ++j)
            #pragma unroll
            for (int i = 0; i < 4; ++i)
                acc[i][j] = MFMA16(fam[i], fb2[j], acc[i][j]);
        __builtin_amdgcn_s_setprio(0);
        __builtin_amdgcn_sched_barrier(0);
        if (s < 7) { asm volatile("s_waitcnt vmcnt(4)" ::: "memory"); }
        else       { asm volatile("s_waitcnt vmcnt(0)" ::: "memory"); }
        __builtin_amdgcn_s_barrier();              // trail: A,B(s+1) rendezvous'd
    }
#undef MFMA16

    // epilogue: S = acc * 2^-13; d = fl(fl(a+b) - 2*S); key = ((d-a)*2^16+32768)<<13 | k
    float bvv[8];
    #pragma unroll
    for (int j = 0; j < 8; ++j) bvv[j] = bsq[k0 + wcol * 128 + j * 16 + lm];
    __syncthreads();                            // LDS reuse for key assembly
    unsigned* lrow = (unsigned*)lds;            // [1024]: (mm>>7)*512 + kh*128 + (mm&127)
    #pragma unroll
    for (int i = 0; i < 4; ++i) {
        #pragma unroll
        for (int r = 0; r < 4; ++r) {
            int mm = wrow * 64 + i * 16 + quad * 4 + r;     // [0,256)
            float av_ = asq[n0 + mm];
            #pragma unroll
            for (int jh = 0; jh < 2; ++jh) {
                unsigned best = 0xFFFFFFFFu;
                #pragma unroll
                for (int j4 = 0; j4 < 4; ++j4) {
                    const int j = jh * 4 + j4;
                    float S = acc[i][j][r] * 1.220703125e-4f;   // * 2^-13
                    float dd = (av_ + bvv[j]) - 2.0f * S;
                    float gv = dd - av_;                        // exact (Sterbenz)
                    int mi = (int)(gv * 65536.0f) + 32768;      // exact integer
                    int col = k0 + wcol * 128 + j * 16 + lm;
                    unsigned key = ((unsigned)mi << 13) | (unsigned)col;
                    best = key < best ? key : best;
                }
                #pragma unroll
                for (int xm = 1; xm < 16; xm <<= 1) {           // reduce over lm per quad
                    unsigned o = __shfl_xor(best, xm, 64);
                    best = o < best ? o : best;
                }
                if (lm == 0)
                    lrow[(mm >> 7) * 512 + (wcol * 2 + jh) * 128 + (mm & 127)] = best;
            }
        }
    }
    __syncthreads();
    // dense coalesced store: pdk[(nt2)*128 + kt*4 + kh][n&127]; 1024 entries, 2/thread
    #pragma unroll
    for (int u = 0; u < 2; ++u) {
        int e = t + u * 512;
        pdk[((size_t)(nt * 2 + (e >> 9)) * 128 + kt * 4 + ((e >> 7) & 3)) * 128 + (e & 127)]
            = lrow[e];
    }
}

// ---- fused: per-block key reduce -> idx | lists/histogram/cs-sum (y==0) | z_q + loss ----
__global__ __launch_bounds__(256) void k_zqr(const unsigned* __restrict__ pdk,
        const float* __restrict__ z, const float* __restrict__ emb, const float* __restrict__ cs,
        float* __restrict__ out_idx, int* __restrict__ cnt,
        int* __restrict__ head, int* __restrict__ nxt,
        float* __restrict__ out_zq, float* __restrict__ scal) {
    const int bx = blockIdx.x, by = blockIdx.y;
    const int n0 = bx * 64, c00 = by * 64;
    const int lane = threadIdx.x & 63, g = threadIdx.x >> 6;
    const int nt = bx >> 1, mb = (bx & 1) * 64;

    // phase 1: min over 128 j-rows for the block's 64 n; lane l ends with n0+l's key
    unsigned mn = 0xFFFFFFFFu;
    const unsigned* base = pdk + (((size_t)nt * 128 + g * 32) << 7) + mb + lane;
    #pragma unroll 8
    for (int jj = 0; jj < 32; ++jj) {
        unsigned key = base[jj << 7];          // coalesced 256B run per j
        mn = key < mn ? key : mn;
    }
    __shared__ unsigned part[4][64];
    part[g][lane] = mn;
    __syncthreads();
    unsigned k0v = part[0][lane], k1v = part[1][lane];
    unsigned k2v = part[2][lane], k3v = part[3][lane];
    unsigned f01 = k0v < k1v ? k0v : k1v;
    unsigned f23 = k2v < k3v ? k2v : k3v;
    unsigned fkey = f01 < f23 ? f01 : f23;
    int idxn = (int)(fkey & 8191u);
    int n = n0 + lane;

    if (by == 0) {
        if (g == 0) {
            out_idx[n] = (float)idxn;
            atomicAdd(cnt + idxn, 1);
            int old = atomicExch(head + idxn, n + 1);   // 0 = end-of-list
            nxt[n] = old;
        } else if (g == 1) {
            float cv = cs[n];
            #pragma unroll
            for (int m = 1; m < 64; m <<= 1) cv += __shfl_xor(cv, m, 64);
            if (lane == 0) atomicAdd(scal + 1, cv);
        }
    }

    // phase 2: z_q gather + straight-through write + loss
    int b = n >> 10, hw = n & 1023;
    const float* zr = z + (size_t)b * CHW + hw;
    const float* er = emb + (size_t)idxn * 256;
    float* oz = out_zq + (size_t)b * CHW + hw;
    float ls = 0.f;
    #pragma unroll
    for (int q = 0; q < 4; ++q) {
        int c = c00 + g * 16 + q * 4;
        float4 e4 = *(const float4*)(er + c);
        float ev[4] = {e4.x, e4.y, e4.z, e4.w};
        #pragma unroll
        for (int r = 0; r < 4; ++r) {
            float zp = zr[(size_t)(c + r) << 10];
            float dif = ev[r] - zp;
            oz[(size_t)(c + r) << 10] = zp + dif;
            ls = fmaf(dif, dif, ls);
        }
    }
    #pragma unroll
    for (int m = 1; m < 64; m <<= 1) ls += __shfl_xor(ls, m, 64);
    __shared__ float red[4];
    if (lane == 0) red[g] = ls;
    __syncthreads();
    if (threadIdx.x == 0) atomicAdd(scal, red[0] + red[1] + red[2] + red[3]);
}

// ---- finalize: list-walk dw (zf reconstructed from Ah/Am), new_cs, ema, embedding, loss ----
__global__ __launch_bounds__(256) void k_fin(const float* __restrict__ cs, const float* __restrict__ ema,
        const int* __restrict__ head, const int* __restrict__ nxt,
        const _Float16* __restrict__ Ah, const _Float16* __restrict__ Am,
        const float* __restrict__ scal, const int* __restrict__ cnt,
        float* __restrict__ out_ncs, float* __restrict__ out_ema,
        float* __restrict__ out_emb, float* __restrict__ out_loss) {
    int k = blockIdx.x * 4 + (threadIdx.x >> 6);
    int lane = threadIdx.x & 63;
    // dw[k][:] = sum over assigned n of zf[n][:], zf ~= h + m' (m' unscaled residual)
    float4 dwv = {0.f, 0.f, 0.f, 0.f};
    int cur = head[k];
    while (cur) {
        int n = cur - 1;
        v4h hh = *(const v4h*)(Ah + (size_t)n * 256 + lane * 4);
        v4h mm = *(const v4h*)(Am + (size_t)n * 256 + lane * 4);
        dwv.x += (float)hh[0] + (float)mm[0];
        dwv.y += (float)hh[1] + (float)mm[1];
        dwv.z += (float)hh[2] + (float)mm[2];
        dwv.w += (float)hh[3] + (float)mm[3];
        cur = nxt[n];
    }
    const float C1 = (float)(1.0 - 0.99);
    const float KEPS = (float)(8192 * 1e-5);
    float ncs0v = cs[k] * 0.99f + C1 * (float)cnt[k];
    float nsum = 0.99f * scal[1] + C1 * 8192.0f;   // sum(counts) == N == 8192
    float ncs = (ncs0v + 1e-5f) / (nsum + KEPS) * nsum;
    if (lane == 0) out_ncs[k] = ncs;
    size_t base = (size_t)k * 256 + lane * 4;
    float4 e4 = *(const float4*)(ema + base);
    float r0 = e4.x * 0.99f + C1 * dwv.x;
    float r1 = e4.y * 0.99f + C1 * dwv.y;
    float r2 = e4.z * 0.99f + C1 * dwv.z;
    float r3 = e4.w * 0.99f + C1 * dwv.w;
    out_ema[base + 0] = r0; out_ema[base + 1] = r1; out_ema[base + 2] = r2; out_ema[base + 3] = r3;
    out_emb[base + 0] = r0 / ncs; out_emb[base + 1] = r1 / ncs;
    out_emb[base + 2] = r2 / ncs; out_emb[base + 3] = r3 / ncs;
    if (blockIdx.x == 0 && threadIdx.x == 0) {
        float m = scal[0] * (1.0f / 2097152.0f);
        out_loss[0] = m + 0.25f * m;
    }
}

extern "C" void kernel_launch(void* const* d_in, const int* in_sizes, int n_in,
                              void* d_out, int out_size, void* d_ws, size_t ws_size,
                              hipStream_t stream) {
    const float* z   = (const float*)d_in[0];
    const float* emb = (const float*)d_in[1];
    const float* cs  = (const float*)d_in[2];
    const float* ema = (const float*)d_in[3];
    float* out = (float*)d_out;
    float* wsf = (float*)d_ws;

    float* asq  = wsf + OFF_ASQ;
    float* bsq  = wsf + OFF_BSQ;
    int*   cnt  = (int*)(wsf + OFF_CNT);
    int*   head = (int*)(wsf + OFF_HEAD);
    int*   nxt  = (int*)(wsf + OFF_NXT);
    float* scal = wsf + OFF_SCAL;
    _Float16* Ah = (_Float16*)(wsf + OFF_AH);
    _Float16* Am = (_Float16*)(wsf + OFF_AM);
    _Float16* Bh = (_Float16*)(wsf + OFF_BH);
    _Float16* Bm = (_Float16*)(wsf + OFF_BM);

    float* out_zq   = out;                 // [2097152]
    float* out_loss = out + 2097152;       // [1]
    float* out_idx  = out + 2097153;       // [8192]
    float* out_ncs  = out + 2105345;       // [8192]
    float* out_ema  = out + 2113537;       // [2097152]
    float* out_emb  = out + 4210689;       // [2097152]

    // pdk (4 MB) aliases the dead out_ema region: written by k_main, read by k_zqr,
    // overwritten only later by k_fin's out_ema stores.
    unsigned* pdk = (unsigned*)(out + 2113540);   // 16B-aligned

    k_prep<<<2608, 256, 0, stream>>>(z, emb, asq, bsq, Bh, Bm, Ah, Am, wsf + OFF_CNT);
    k_main<<<1024, 512, 0, stream>>>(Ah, Am, Bh, Bm, asq, bsq, pdk);
    k_zqr<<<dim3(128, 4), 256, 0, stream>>>(pdk, z, emb, cs, out_idx, cnt, head, nxt, out_zq, scal);
    k_fin<<<2048, 256, 0, stream>>>(cs, ema, head, nxt, Ah, Am, scal, cnt, out_ncs, out_ema, out_emb, out_loss);
}